// Round 16
// baseline (322.849 us; speedup 1.0000x reference)
//
#include <hip/hip_runtime.h>
#include <cstdint>

#define IN_DIM 128
#define HC 256          // H*C
#define NEG_SLOPE 0.2f
#define BN_EPS 1e-5f
#define LOG2E 1.44269504088896340736f

#define BKT_SHIFT 9     // 512 nodes per bucket
#define BKT_CAP 16384   // slots per bucket region (mean ~8.5k)
#define B_SC 512        // scatter blocks in K1
#define NB_BN 1024      // bn_partial blocks

typedef short bf16x8 __attribute__((ext_vector_type(8)));
typedef float f32x4 __attribute__((ext_vector_type(4)));

#define EXP2F(x) __builtin_amdgcn_exp2f(x)   // native v_exp_f32 = 2^x

__device__ __forceinline__ unsigned short f2bf(float f) {
    union { float f; unsigned int u; } v; v.f = f;
    unsigned int r = (v.u + 0x7FFFu + ((v.u >> 16) & 1u)) >> 16;   // RNE
    return (unsigned short)r;
}
__device__ __forceinline__ float bf2f(unsigned short h) {
    union { unsigned int u; float f; } v; v.u = ((unsigned int)h) << 16;
    return v.f;
}

template<int CTRL>
__device__ __forceinline__ float dppadd(float x) {
    int y = __builtin_amdgcn_update_dpp(0, __builtin_bit_cast(int, x), CTRL, 0xF, 0xF, true);
    return x + __builtin_bit_cast(float, y);
}
__device__ __forceinline__ float red16(float p) {
    p = dppadd<0xB1>(p);
    p = dppadd<0x4E>(p);
    p = dppadd<0x124>(p);
    p = dppadd<0x128>(p);
    return p;
}

__device__ __forceinline__ void unpk(ushort4 u, float* f) {
    f[0] = bf2f(u.x); f[1] = bf2f(u.y); f[2] = bf2f(u.z); f[3] = bf2f(u.w);
}
__device__ __forceinline__ float esc(const float* f, float x0, float x1, float x2, float x3,
                                     float4 a) {
    float z0 = f[0] + x0, z1 = f[1] + x1, z2 = f[2] + x2, z3 = f[3] + x3;
    float p = a.x * fmaxf(z0, NEG_SLOPE * z0);
    p = fmaf(a.y, fmaxf(z1, NEG_SLOPE * z1), p);
    p = fmaf(a.z, fmaxf(z2, NEG_SLOPE * z2), p);
    p = fmaf(a.w, fmaxf(z3, NEG_SLOPE * z3), p);
    return p;
}

// ========== prep: cast_w (blocks 0..31) | zero bucket cursors (block 32) ==========
__global__ __launch_bounds__(256) void prep(
    const float* __restrict__ Wl, const float* __restrict__ Wr,
    unsigned short* __restrict__ Wfrag, int* __restrict__ gcur)
{
    int b = blockIdx.x;
    if (b < 32) {
        int ob = b * 4 + (threadIdx.x >> 6);
        int j = ob >> 2;
        int kk = ob & 3;
        int l = threadIdx.x & 63;
        int col = j * 16 + (l & 15);
        const float* W = (col < 256) ? Wl : Wr;
        int c = col & 255;
        unsigned short tmp[8];
#pragma unroll
        for (int m = 0; m < 8; ++m) {
            int k = kk * 32 + ((l >> 4) << 3) + m;
            tmp[m] = f2bf(W[(size_t)k * 256 + c]);
        }
        ulonglong2* dst = (ulonglong2*)(Wfrag + ((size_t)(j * 4 + kk) * 64 + l) * 8);
        *dst = *(ulonglong2*)tmp;
    } else {
        gcur[threadIdx.x] = 0;     // 256 bucket cursors
    }
}

// ========== K1: bucket scatter (blocks 0..B_SC) || gemm w/ inline F cast ==========
__global__ __launch_bounds__(256) void scatter_gemm(
    const float* __restrict__ F, const unsigned short* __restrict__ Wfrag,
    const float* __restrict__ bl, const float* __restrict__ br,
    unsigned short* __restrict__ xl, unsigned short* __restrict__ xr,
    const int* __restrict__ ei, int* __restrict__ gcur, int2* __restrict__ bucketBuf,
    int E, int n, int ntiles)
{
    int b = blockIdx.x;
    if (b < B_SC) {
        __shared__ int hist[256];
        __shared__ int base[256];
        int t = threadIdx.x;
        hist[t] = 0;
        __syncthreads();
        int ept = (E + B_SC - 1) / B_SC;
        int beg = b * ept;
        int endc = min(beg + ept, E);
        for (int e = beg + t; e < endc; e += 256) {
            int dst = ei[(size_t)E + e];
            atomicAdd(&hist[dst >> BKT_SHIFT], 1);
        }
        __syncthreads();
        int h = hist[t];
        if (h > 0) base[t] = atomicAdd(&gcur[t], h);
        hist[t] = 0;               // reuse as local placed counter
        __syncthreads();
        for (int e = beg + t; e < endc; e += 256) {
            int src = ei[e];
            int dst = ei[(size_t)E + e];
            int bk = dst >> BKT_SHIFT;
            int r = atomicAdd(&hist[bk], 1);
            int pos = base[bk] + r;
            if (pos < BKT_CAP) {
                int2 v; v.x = src; v.y = dst;
                bucketBuf[(size_t)bk * BKT_CAP + pos] = v;
            }
        }
        return;
    }
    // ---- MFMA GEMM, A-fragments loaded straight from fp32 F ----
    int i = (b - B_SC) * 4 + (threadIdx.x >> 6);   // row tile
    if (i >= ntiles) return;
    int l = threadIdx.x & 63;

    int row = i * 16 + (l & 15);
    bf16x8 afr[4];
#pragma unroll
    for (int kk = 0; kk < 4; ++kk) {
        int k0 = kk * 32 + ((l >> 4) << 3);
        float4 f0 = make_float4(0.f, 0.f, 0.f, 0.f), f1 = f0;
        if (row < n) {
            const float* p = F + (size_t)row * IN_DIM + k0;
            f0 = *(const float4*)p;
            f1 = *(const float4*)(p + 4);
        }
        unsigned short tmp[8];
        tmp[0] = f2bf(f0.x); tmp[1] = f2bf(f0.y); tmp[2] = f2bf(f0.z); tmp[3] = f2bf(f0.w);
        tmp[4] = f2bf(f1.x); tmp[5] = f2bf(f1.y); tmp[6] = f2bf(f1.z); tmp[7] = f2bf(f1.w);
        afr[kk] = *(bf16x8*)tmp;
    }

    const bf16x8* wv = (const bf16x8*)Wfrag + l;
    int cl = l & 15;
    int rbase = i * 16 + ((l >> 4) << 2);

#pragma unroll 4
    for (int j = 0; j < 32; ++j) {
        const bf16x8* bp = wv + (size_t)j * 4 * 64;
        f32x4 acc = {0.f, 0.f, 0.f, 0.f};
        acc = __builtin_amdgcn_mfma_f32_16x16x32_bf16(afr[0], bp[0 * 64], acc, 0, 0, 0);
        acc = __builtin_amdgcn_mfma_f32_16x16x32_bf16(afr[1], bp[1 * 64], acc, 0, 0, 0);
        acc = __builtin_amdgcn_mfma_f32_16x16x32_bf16(afr[2], bp[2 * 64], acc, 0, 0, 0);
        acc = __builtin_amdgcn_mfma_f32_16x16x32_bf16(afr[3], bp[3 * 64], acc, 0, 0, 0);

        int col = j * 16 + cl;
        unsigned short* X = (col < 256) ? xl : xr;
        int c = col & 255;
        float bv = (col < 256) ? bl[c] : br[c];
#pragma unroll
        for (int q = 0; q < 4; ++q) {
            int r = rbase + q;
            if (r < n) X[(size_t)r * HC + c] = f2bf(acc[q] + bv);
        }
    }
}

// ========== K2: per-bucket CSR build (off + csr_boff), all per-edge atomics in LDS ====
__global__ __launch_bounds__(256) void bucket_build(
    const int2* __restrict__ bucketBuf, const int* __restrict__ gcur,
    int* __restrict__ off, int* __restrict__ csr_boff, int n, int nbkt)
{
    __shared__ int bin[512];
    __shared__ int tmp[256];
    __shared__ int bstart_sh;
    int b = blockIdx.x;
    int t = threadIdx.x;

    int part = (t < b) ? min(gcur[t], BKT_CAP) : 0;
    tmp[t] = part;
    __syncthreads();
    for (int d = 128; d > 0; d >>= 1) {
        if (t < d) tmp[t] += tmp[t + d];
        __syncthreads();
    }
    if (t == 0) bstart_sh = tmp[0];
    __syncthreads();
    int bstart = bstart_sh;
    int cnt_b = min(gcur[b], BKT_CAP);

    bin[t] = 0; bin[t + 256] = 0;
    __syncthreads();

    const int2* buf = bucketBuf + (size_t)b * BKT_CAP;
    int nodeBase = b << BKT_SHIFT;

    for (int i = t; i < cnt_b; i += 256) {
        atomicAdd(&bin[buf[i].y - nodeBase], 1);
    }
    __syncthreads();

    int b0 = bin[2 * t], b1 = bin[2 * t + 1];
    tmp[t] = b0 + b1;
    __syncthreads();
    for (int d = 1; d < 256; d <<= 1) {
        int v = (t >= d) ? tmp[t - d] : 0;
        __syncthreads();
        tmp[t] += v;
        __syncthreads();
    }
    int excl = (t == 0) ? 0 : tmp[t - 1];
    int lo0 = excl, lo1 = excl + b0;

    int n0 = nodeBase + 2 * t, n1 = n0 + 1;
    if (n0 < n) off[n0] = bstart + lo0;
    if (n1 < n) off[n1] = bstart + lo1;
    int nodeEnd = min(nodeBase + 512, n);
    if (t == 0 && nodeEnd == n) off[n] = bstart + cnt_b;

    bin[2 * t] = lo0; bin[2 * t + 1] = lo1;
    __syncthreads();
    for (int i = t; i < cnt_b; i += 256) {
        int2 e = buf[i];
        int r = atomicAdd(&bin[e.y - nodeBase], 1);
        csr_boff[bstart + r] = e.x << 9;     // src * 512 bytes (bf16 row)
    }
}

// -------- per-node wave aggregation: 2-group-deep gather pipeline --------
__global__ __launch_bounds__(256) void gat_agg(
    const unsigned short* __restrict__ xl, const unsigned short* __restrict__ xr,
    const int* __restrict__ csr_boff, const int* __restrict__ off,
    const float* __restrict__ att, const float* __restrict__ bias,
    unsigned short* __restrict__ outb, int n)
{
    int d = (blockIdx.x * blockDim.x + threadIdx.x) >> 6;   // one wave per node
    int lane = threadIdx.x & 63;
    if (d >= n) return;

    const char* xlc = (const char*)xl;
    int lo8 = lane << 3;
    ushort4 xru = ((const ushort4*)xr)[(size_t)d * 64 + lane];
    float xr0 = bf2f(xru.x), xr1 = bf2f(xru.y), xr2 = bf2f(xru.z), xr3 = bf2f(xru.w);
    float4 att4 = *(const float4*)(att + 4 * lane);
    att4.x *= LOG2E; att4.y *= LOG2E; att4.z *= LOG2E; att4.w *= LOG2E;

    int beg = __builtin_amdgcn_readfirstlane(off[d]);
    int end = __builtin_amdgcn_readfirstlane(off[d + 1]);

    // self-loop (source row = d), not in CSR
    float ax, ay, az, aw, lsum;
    {
        ushort4 t0 = *(const ushort4*)(xlc + ((size_t)d << 9) + lo8);
        float f0[4];
        unpk(t0, f0);
        float p0 = esc(f0, xr0, xr1, xr2, xr3, att4);
        p0 = red16(p0);
        float e0 = EXP2F(p0);
        ax = e0 * f0[0]; ay = e0 * f0[1]; az = e0 * f0[2]; aw = e0 * f0[3];
        lsum = e0;
    }

    int nmain = (end - beg) & ~3;
    int imend = beg + nmain;
    int i = beg;

    ushort4 u0, u1, u2, u3;        // group at i
    ushort4 v0, v1, v2, v3;        // group at i+4
    if (i < imend) {
        int b0 = __builtin_amdgcn_readfirstlane(csr_boff[i]);
        int b1 = __builtin_amdgcn_readfirstlane(csr_boff[i + 1]);
        int b2 = __builtin_amdgcn_readfirstlane(csr_boff[i + 2]);
        int b3 = __builtin_amdgcn_readfirstlane(csr_boff[i + 3]);
        u0 = *(const ushort4*)(xlc + b0 + lo8);
        u1 = *(const ushort4*)(xlc + b1 + lo8);
        u2 = *(const ushort4*)(xlc + b2 + lo8);
        u3 = *(const ushort4*)(xlc + b3 + lo8);
    }
    if (i + 4 < imend) {
        int b0 = __builtin_amdgcn_readfirstlane(csr_boff[i + 4]);
        int b1 = __builtin_amdgcn_readfirstlane(csr_boff[i + 5]);
        int b2 = __builtin_amdgcn_readfirstlane(csr_boff[i + 6]);
        int b3 = __builtin_amdgcn_readfirstlane(csr_boff[i + 7]);
        v0 = *(const ushort4*)(xlc + b0 + lo8);
        v1 = *(const ushort4*)(xlc + b1 + lo8);
        v2 = *(const ushort4*)(xlc + b2 + lo8);
        v3 = *(const ushort4*)(xlc + b3 + lo8);
    }
    while (i < imend) {
        ushort4 c0 = u0, c1 = u1, c2 = u2, c3 = u3;
        u0 = v0; u1 = v1; u2 = v2; u3 = v3;
        int ipf = i + 8;
        if (ipf < imend) {         // prefetch 2 groups ahead
            int b0 = __builtin_amdgcn_readfirstlane(csr_boff[ipf]);
            int b1 = __builtin_amdgcn_readfirstlane(csr_boff[ipf + 1]);
            int b2 = __builtin_amdgcn_readfirstlane(csr_boff[ipf + 2]);
            int b3 = __builtin_amdgcn_readfirstlane(csr_boff[ipf + 3]);
            v0 = *(const ushort4*)(xlc + b0 + lo8);
            v1 = *(const ushort4*)(xlc + b1 + lo8);
            v2 = *(const ushort4*)(xlc + b2 + lo8);
            v3 = *(const ushort4*)(xlc + b3 + lo8);
        }
        float f0[4], f1[4], f2[4], f3[4];
        unpk(c0, f0); unpk(c1, f1); unpk(c2, f2); unpk(c3, f3);

        float p0 = esc(f0, xr0, xr1, xr2, xr3, att4);
        float p1 = esc(f1, xr0, xr1, xr2, xr3, att4);
        float p2 = esc(f2, xr0, xr1, xr2, xr3, att4);
        float p3 = esc(f3, xr0, xr1, xr2, xr3, att4);

        p0 = dppadd<0xB1>(p0);  p1 = dppadd<0xB1>(p1);  p2 = dppadd<0xB1>(p2);  p3 = dppadd<0xB1>(p3);
        p0 = dppadd<0x4E>(p0);  p1 = dppadd<0x4E>(p1);  p2 = dppadd<0x4E>(p2);  p3 = dppadd<0x4E>(p3);
        p0 = dppadd<0x124>(p0); p1 = dppadd<0x124>(p1); p2 = dppadd<0x124>(p2); p3 = dppadd<0x124>(p3);
        p0 = dppadd<0x128>(p0); p1 = dppadd<0x128>(p1); p2 = dppadd<0x128>(p2); p3 = dppadd<0x128>(p3);

        float e0 = EXP2F(p0), e1 = EXP2F(p1);
        float e2 = EXP2F(p2), e3 = EXP2F(p3);
        ax = fmaf(e0, f0[0], fmaf(e1, f1[0], fmaf(e2, f2[0], fmaf(e3, f3[0], ax))));
        ay = fmaf(e0, f0[1], fmaf(e1, f1[1], fmaf(e2, f2[1], fmaf(e3, f3[1], ay))));
        az = fmaf(e0, f0[2], fmaf(e1, f1[2], fmaf(e2, f2[2], fmaf(e3, f3[2], az))));
        aw = fmaf(e0, f0[3], fmaf(e1, f1[3], fmaf(e2, f2[3], fmaf(e3, f3[3], aw))));
        lsum += (e0 + e1) + (e2 + e3);
        i += 4;
    }
    for (; i < end; ++i) {                 // tail (0..3 edges)
        int b0 = __builtin_amdgcn_readfirstlane(csr_boff[i]);
        ushort4 t0 = *(const ushort4*)(xlc + b0 + lo8);
        float f0[4];
        unpk(t0, f0);
        float p0 = esc(f0, xr0, xr1, xr2, xr3, att4);
        p0 = red16(p0);
        float e0 = EXP2F(p0);
        ax = fmaf(e0, f0[0], ax); ay = fmaf(e0, f0[1], ay);
        az = fmaf(e0, f0[2], az); aw = fmaf(e0, f0[3], aw);
        lsum += e0;
    }

    float inv = 1.f / (lsum + 1e-16f);
    float4 b4 = *(const float4*)(bias + 4 * lane);
    ushort4 o;
    o.x = f2bf(fmaf(ax, inv, b4.x));
    o.y = f2bf(fmaf(ay, inv, b4.y));
    o.z = f2bf(fmaf(az, inv, b4.z));
    o.w = f2bf(fmaf(aw, inv, b4.w));
    ((ushort4*)outb)[(size_t)d * 64 + lane] = o;
}

// ---------------- BatchNorm (bf16 input path) ----------------
__global__ __launch_bounds__(256) void bn_partial(const unsigned short* __restrict__ outb,
                                                  float* __restrict__ partials, int n)
{
    int c = threadIdx.x;
    int b = blockIdx.x;
    int chunk = (n + NB_BN - 1) / NB_BN;
    int beg = b * chunk;
    int end = min(beg + chunk, n);
    float s = 0.f, s2 = 0.f;
    for (int r = beg; r < end; ++r) {
        float v = bf2f(outb[(size_t)r * HC + c]);
        s += v; s2 += v * v;
    }
    partials[(size_t)b * 512 + c] = s;
    partials[(size_t)b * 512 + 256 + c] = s2;
}

// one block per channel
__global__ __launch_bounds__(256) void bn_final(const float* __restrict__ partials,
                                                float* __restrict__ stats, int n)
{
    int c = blockIdx.x;
    int t = threadIdx.x;
    float s = 0.f, s2 = 0.f;
    for (int b = t; b < NB_BN; b += 256) {
        s  += partials[(size_t)b * 512 + c];
        s2 += partials[(size_t)b * 512 + 256 + c];
    }
    __shared__ float rs[256], rs2[256];
    rs[t] = s; rs2[t] = s2;
    __syncthreads();
    for (int d = 128; d > 0; d >>= 1) {
        if (t < d) { rs[t] += rs[t + d]; rs2[t] += rs2[t + d]; }
        __syncthreads();
    }
    if (t == 0) {
        float mean = rs[0] / (float)n;
        float var = rs2[0] / (float)n - mean * mean;
        stats[c] = mean;
        stats[256 + c] = rsqrtf(var + BN_EPS);
    }
}

__global__ void bn_apply(const unsigned short* __restrict__ outb,
                         const float* __restrict__ stats,
                         const float* __restrict__ gamma, const float* __restrict__ beta,
                         float* __restrict__ out, long long total4)
{
    long long stride = (long long)gridDim.x * blockDim.x;
    for (long long i = blockIdx.x * (long long)blockDim.x + threadIdx.x; i < total4;
         i += stride) {
        int cb = ((int)(i & 63)) * 4;
        ushort4 u = ((const ushort4*)outb)[i];
        float4 o;
        o.x = fmaxf(0.f, (bf2f(u.x) - stats[cb + 0]) * stats[256 + cb + 0] * gamma[cb + 0] + beta[cb + 0]);
        o.y = fmaxf(0.f, (bf2f(u.y) - stats[cb + 1]) * stats[256 + cb + 1] * gamma[cb + 1] + beta[cb + 1]);
        o.z = fmaxf(0.f, (bf2f(u.z) - stats[cb + 2]) * stats[256 + cb + 2] * gamma[cb + 2] + beta[cb + 2]);
        o.w = fmaxf(0.f, (bf2f(u.w) - stats[cb + 3]) * stats[256 + cb + 3] * gamma[cb + 3] + beta[cb + 3]);
        ((float4*)out)[i] = o;
    }
}

// ---------------- launch ----------------
extern "C" void kernel_launch(void* const* d_in, const int* in_sizes, int n_in,
                              void* d_out, int out_size, void* d_ws, size_t ws_size,
                              hipStream_t stream)
{
    const float* feature = (const float*)d_in[0];
    const int* ei        = (const int*)d_in[1];
    const float* Wl   = (const float*)d_in[2];
    const float* bl   = (const float*)d_in[3];
    const float* Wr   = (const float*)d_in[4];
    const float* br   = (const float*)d_in[5];
    const float* att  = (const float*)d_in[6];
    const float* bias = (const float*)d_in[7];
    const float* gamma = (const float*)d_in[8];
    const float* beta  = (const float*)d_in[9];

    const int n = in_sizes[0] / IN_DIM;
    const int E = in_sizes[1] / 2;
    const int ntiles = (n + 15) / 16;
    const int nbkt = (n + 511) >> 9;

    char* ws = (char*)d_ws;
    size_t o = 0;
    auto carve = [&](size_t bytes) -> void* {
        void* p = ws + o; o = (o + bytes + 15) & ~(size_t)15; return p;
    };
    unsigned short* xl    = (unsigned short*)carve((size_t)n * HC * sizeof(short));
    unsigned short* xr    = (unsigned short*)carve((size_t)n * HC * sizeof(short));
    unsigned short* outb  = (unsigned short*)carve((size_t)n * HC * sizeof(short));
    unsigned short* Wfrag = (unsigned short*)carve((size_t)32 * 4 * 64 * 8 * sizeof(short));
    int2* bucketBuf = (int2*)carve((size_t)256 * BKT_CAP * sizeof(int2));
    int*  csr_boff  = (int*)carve((size_t)E * sizeof(int));
    int*  off       = (int*)carve((size_t)(n + 1) * sizeof(int));
    int*  gcur      = (int*)carve(256 * sizeof(int));
    float* partials = (float*)carve((size_t)NB_BN * 512 * sizeof(float));
    float* stats    = (float*)carve(512 * sizeof(float));
    float* outf = (float*)d_out;

    if (o > ws_size) return;

    // 1. prep: cast W fragments + zero bucket cursors
    prep<<<33, 256, 0, stream>>>(Wl, Wr, Wfrag, gcur);

    // 2. K1: bucket scatter || gemm
    scatter_gemm<<<B_SC + (ntiles + 3) / 4, 256, 0, stream>>>(
        feature, Wfrag, bl, br, xl, xr, ei, gcur, bucketBuf, E, n, ntiles);

    // 3. K2: per-bucket CSR build
    bucket_build<<<nbkt, 256, 0, stream>>>(bucketBuf, gcur, off, csr_boff, n, nbkt);

    // 4. per-node aggregation (2-group-deep pipeline)
    int agg_blocks = (n + 3) / 4;
    gat_agg<<<agg_blocks, 256, 0, stream>>>(xl, xr, csr_boff, off, att, bias, outb, n);

    // 5. BN partial + finalize + apply
    bn_partial<<<NB_BN, 256, 0, stream>>>(outb, partials, n);
    bn_final<<<256, 256, 0, stream>>>(partials, stats, n);
    long long total4 = (long long)n * (HC / 4);
    bn_apply<<<4096, 256, 0, stream>>>(outb, stats, gamma, beta, outf, total4);
}

// Round 17
// 316.595 us; speedup vs baseline: 1.0198x; 1.0198x over previous
//
#include <hip/hip_runtime.h>
#include <cstdint>

#define IN_DIM 128
#define HC 256          // H*C
#define NEG_SLOPE 0.2f
#define BN_EPS 1e-5f
#define LOG2E 1.44269504088896340736f

#define BKT_SHIFT 9     // 512 nodes per bucket
#define BKT_CAP 16384   // slots per bucket region (mean ~8.5k)
#define B_SC 768        // scatter blocks in K1
#define CHUNK_MAX 2304  // max edges per scatter chunk (E/B_SC = 2084 for E=1.6M)
#define NB_BN 1024      // bn_partial blocks

typedef short bf16x8 __attribute__((ext_vector_type(8)));
typedef float f32x4 __attribute__((ext_vector_type(4)));

#define EXP2F(x) __builtin_amdgcn_exp2f(x)   // native v_exp_f32 = 2^x

__device__ __forceinline__ unsigned short f2bf(float f) {
    union { float f; unsigned int u; } v; v.f = f;
    unsigned int r = (v.u + 0x7FFFu + ((v.u >> 16) & 1u)) >> 16;   // RNE
    return (unsigned short)r;
}
__device__ __forceinline__ float bf2f(unsigned short h) {
    union { unsigned int u; float f; } v; v.u = ((unsigned int)h) << 16;
    return v.f;
}

template<int CTRL>
__device__ __forceinline__ float dppadd(float x) {
    int y = __builtin_amdgcn_update_dpp(0, __builtin_bit_cast(int, x), CTRL, 0xF, 0xF, true);
    return x + __builtin_bit_cast(float, y);
}
__device__ __forceinline__ float red16(float p) {
    p = dppadd<0xB1>(p);
    p = dppadd<0x4E>(p);
    p = dppadd<0x124>(p);
    p = dppadd<0x128>(p);
    return p;
}

__device__ __forceinline__ void unpk(ushort4 u, float* f) {
    f[0] = bf2f(u.x); f[1] = bf2f(u.y); f[2] = bf2f(u.z); f[3] = bf2f(u.w);
}
__device__ __forceinline__ float esc(const float* f, float x0, float x1, float x2, float x3,
                                     float4 a) {
    float z0 = f[0] + x0, z1 = f[1] + x1, z2 = f[2] + x2, z3 = f[3] + x3;
    float p = a.x * fmaxf(z0, NEG_SLOPE * z0);
    p = fmaf(a.y, fmaxf(z1, NEG_SLOPE * z1), p);
    p = fmaf(a.z, fmaxf(z2, NEG_SLOPE * z2), p);
    p = fmaf(a.w, fmaxf(z3, NEG_SLOPE * z3), p);
    return p;
}

// ========== prep: cast_w (blocks 0..31) | zero bucket cursors (block 32) ==========
__global__ __launch_bounds__(256) void prep(
    const float* __restrict__ Wl, const float* __restrict__ Wr,
    unsigned short* __restrict__ Wfrag, int* __restrict__ gcur)
{
    int b = blockIdx.x;
    if (b < 32) {
        int ob = b * 4 + (threadIdx.x >> 6);
        int j = ob >> 2;
        int kk = ob & 3;
        int l = threadIdx.x & 63;
        int col = j * 16 + (l & 15);
        const float* W = (col < 256) ? Wl : Wr;
        int c = col & 255;
        unsigned short tmp[8];
#pragma unroll
        for (int m = 0; m < 8; ++m) {
            int k = kk * 32 + ((l >> 4) << 3) + m;
            tmp[m] = f2bf(W[(size_t)k * 256 + c]);
        }
        ulonglong2* dst = (ulonglong2*)(Wfrag + ((size_t)(j * 4 + kk) * 64 + l) * 8);
        *dst = *(ulonglong2*)tmp;
    } else {
        gcur[threadIdx.x] = 0;     // 256 bucket cursors
    }
}

// ========== K1: LDS-staged sorted-run bucket scatter (blocks 0..B_SC) || gemm ==========
__global__ __launch_bounds__(256) void scatter_gemm(
    const float* __restrict__ F, const unsigned short* __restrict__ Wfrag,
    const float* __restrict__ bl, const float* __restrict__ br,
    unsigned short* __restrict__ xl, unsigned short* __restrict__ xr,
    const int* __restrict__ ei, int* __restrict__ gcur, int2* __restrict__ bucketBuf,
    int E, int n, int ntiles)
{
    int b = blockIdx.x;
    if (b < B_SC) {
        __shared__ int2 eL[CHUNK_MAX];        // 18.4 KB
        __shared__ int2 sortedL[CHUNK_MAX];   // 18.4 KB
        __shared__ int hist[256];             // also cursor
        __shared__ int lofs[256];
        __shared__ int base[256];
        int t = threadIdx.x;
        int ept = (E + B_SC - 1) / B_SC;
        int beg = b * ept;
        int cnt = E - beg;
        if (cnt > ept) cnt = ept;
        if (cnt < 0) cnt = 0;
        if (ept > CHUNK_MAX) return;          // safety (never for this problem size)

        // stage edges in LDS (single global read of the chunk)
        for (int k = t; k < cnt; k += 256) {
            int2 v;
            v.x = ei[beg + k];
            v.y = ei[(size_t)E + beg + k];
            eL[k] = v;
        }
        hist[t] = 0;
        __syncthreads();
        // LDS histogram of 256 buckets
        for (int k = t; k < cnt; k += 256) atomicAdd(&hist[eL[k].y >> BKT_SHIFT], 1);
        __syncthreads();
        int h = hist[t];
        // inclusive scan of hist -> lofs
        lofs[t] = h;
        __syncthreads();
        for (int dl = 1; dl < 256; dl <<= 1) {
            int v = (t >= dl) ? lofs[t - dl] : 0;
            __syncthreads();
            lofs[t] += v;
            __syncthreads();
        }
        int excl = lofs[t] - h;
        // one global atomic per non-empty bucket
        if (h > 0) base[t] = atomicAdd(&gcur[t], h);
        hist[t] = excl;       // cursor
        __syncthreads();
        lofs[t] = excl;       // keep exclusive offset for position calc
        __syncthreads();
        // LDS counting-sort by bucket
        for (int k = t; k < cnt; k += 256) {
            int2 e = eL[k];
            int r = atomicAdd(&hist[e.y >> BKT_SHIFT], 1);
            sortedL[r] = e;
        }
        __syncthreads();
        // coalesced write-out: consecutive k within a bucket run -> consecutive global
        for (int k = t; k < cnt; k += 256) {
            int2 e = sortedL[k];
            int bk = e.y >> BKT_SHIFT;
            int pos = base[bk] + (k - lofs[bk]);
            if (pos < BKT_CAP) bucketBuf[(size_t)bk * BKT_CAP + pos] = e;
        }
        return;
    }
    // ---- MFMA GEMM, A-fragments loaded straight from fp32 F ----
    int i = (b - B_SC) * 4 + (threadIdx.x >> 6);   // row tile
    if (i >= ntiles) return;
    int l = threadIdx.x & 63;

    int row = i * 16 + (l & 15);
    bf16x8 afr[4];
#pragma unroll
    for (int kk = 0; kk < 4; ++kk) {
        int k0 = kk * 32 + ((l >> 4) << 3);
        float4 f0 = make_float4(0.f, 0.f, 0.f, 0.f), f1 = f0;
        if (row < n) {
            const float* p = F + (size_t)row * IN_DIM + k0;
            f0 = *(const float4*)p;
            f1 = *(const float4*)(p + 4);
        }
        unsigned short tmp[8];
        tmp[0] = f2bf(f0.x); tmp[1] = f2bf(f0.y); tmp[2] = f2bf(f0.z); tmp[3] = f2bf(f0.w);
        tmp[4] = f2bf(f1.x); tmp[5] = f2bf(f1.y); tmp[6] = f2bf(f1.z); tmp[7] = f2bf(f1.w);
        afr[kk] = *(bf16x8*)tmp;
    }

    const bf16x8* wv = (const bf16x8*)Wfrag + l;
    int cl = l & 15;
    int rbase = i * 16 + ((l >> 4) << 2);

#pragma unroll 4
    for (int j = 0; j < 32; ++j) {
        const bf16x8* bp = wv + (size_t)j * 4 * 64;
        f32x4 acc = {0.f, 0.f, 0.f, 0.f};
        acc = __builtin_amdgcn_mfma_f32_16x16x32_bf16(afr[0], bp[0 * 64], acc, 0, 0, 0);
        acc = __builtin_amdgcn_mfma_f32_16x16x32_bf16(afr[1], bp[1 * 64], acc, 0, 0, 0);
        acc = __builtin_amdgcn_mfma_f32_16x16x32_bf16(afr[2], bp[2 * 64], acc, 0, 0, 0);
        acc = __builtin_amdgcn_mfma_f32_16x16x32_bf16(afr[3], bp[3 * 64], acc, 0, 0, 0);

        int col = j * 16 + cl;
        unsigned short* X = (col < 256) ? xl : xr;
        int c = col & 255;
        float bv = (col < 256) ? bl[c] : br[c];
#pragma unroll
        for (int q = 0; q < 4; ++q) {
            int r = rbase + q;
            if (r < n) X[(size_t)r * HC + c] = f2bf(acc[q] + bv);
        }
    }
}

// ========== K2: per-bucket CSR build (off + csr_boff), all per-edge atomics in LDS ====
__global__ __launch_bounds__(256) void bucket_build(
    const int2* __restrict__ bucketBuf, const int* __restrict__ gcur,
    int* __restrict__ off, int* __restrict__ csr_boff, int n, int nbkt)
{
    __shared__ int bin[512];
    __shared__ int tmp[256];
    __shared__ int bstart_sh;
    int b = blockIdx.x;
    int t = threadIdx.x;

    int part = (t < b) ? min(gcur[t], BKT_CAP) : 0;
    tmp[t] = part;
    __syncthreads();
    for (int d = 128; d > 0; d >>= 1) {
        if (t < d) tmp[t] += tmp[t + d];
        __syncthreads();
    }
    if (t == 0) bstart_sh = tmp[0];
    __syncthreads();
    int bstart = bstart_sh;
    int cnt_b = min(gcur[b], BKT_CAP);

    bin[t] = 0; bin[t + 256] = 0;
    __syncthreads();

    const int2* buf = bucketBuf + (size_t)b * BKT_CAP;
    int nodeBase = b << BKT_SHIFT;

    for (int i = t; i < cnt_b; i += 256) {
        atomicAdd(&bin[buf[i].y - nodeBase], 1);
    }
    __syncthreads();

    int b0 = bin[2 * t], b1 = bin[2 * t + 1];
    tmp[t] = b0 + b1;
    __syncthreads();
    for (int d = 1; d < 256; d <<= 1) {
        int v = (t >= d) ? tmp[t - d] : 0;
        __syncthreads();
        tmp[t] += v;
        __syncthreads();
    }
    int excl = (t == 0) ? 0 : tmp[t - 1];
    int lo0 = excl, lo1 = excl + b0;

    int n0 = nodeBase + 2 * t, n1 = n0 + 1;
    if (n0 < n) off[n0] = bstart + lo0;
    if (n1 < n) off[n1] = bstart + lo1;
    int nodeEnd = min(nodeBase + 512, n);
    if (t == 0 && nodeEnd == n) off[n] = bstart + cnt_b;

    bin[2 * t] = lo0; bin[2 * t + 1] = lo1;
    __syncthreads();
    for (int i = t; i < cnt_b; i += 256) {
        int2 e = buf[i];
        int r = atomicAdd(&bin[e.y - nodeBase], 1);
        csr_boff[bstart + r] = e.x << 9;     // src * 512 bytes (bf16 row)
    }
}

// -------- per-node wave aggregation: 2-group-deep gather pipeline --------
__global__ __launch_bounds__(256) void gat_agg(
    const unsigned short* __restrict__ xl, const unsigned short* __restrict__ xr,
    const int* __restrict__ csr_boff, const int* __restrict__ off,
    const float* __restrict__ att, const float* __restrict__ bias,
    unsigned short* __restrict__ outb, int n)
{
    int d = (blockIdx.x * blockDim.x + threadIdx.x) >> 6;   // one wave per node
    int lane = threadIdx.x & 63;
    if (d >= n) return;

    const char* xlc = (const char*)xl;
    int lo8 = lane << 3;
    ushort4 xru = ((const ushort4*)xr)[(size_t)d * 64 + lane];
    float xr0 = bf2f(xru.x), xr1 = bf2f(xru.y), xr2 = bf2f(xru.z), xr3 = bf2f(xru.w);
    float4 att4 = *(const float4*)(att + 4 * lane);
    att4.x *= LOG2E; att4.y *= LOG2E; att4.z *= LOG2E; att4.w *= LOG2E;

    int beg = __builtin_amdgcn_readfirstlane(off[d]);
    int end = __builtin_amdgcn_readfirstlane(off[d + 1]);

    // self-loop (source row = d), not in CSR
    float ax, ay, az, aw, lsum;
    {
        ushort4 t0 = *(const ushort4*)(xlc + ((size_t)d << 9) + lo8);
        float f0[4];
        unpk(t0, f0);
        float p0 = esc(f0, xr0, xr1, xr2, xr3, att4);
        p0 = red16(p0);
        float e0 = EXP2F(p0);
        ax = e0 * f0[0]; ay = e0 * f0[1]; az = e0 * f0[2]; aw = e0 * f0[3];
        lsum = e0;
    }

    int nmain = (end - beg) & ~3;
    int imend = beg + nmain;
    int i = beg;

    ushort4 u0, u1, u2, u3;        // group at i
    ushort4 v0, v1, v2, v3;        // group at i+4
    if (i < imend) {
        int b0 = __builtin_amdgcn_readfirstlane(csr_boff[i]);
        int b1 = __builtin_amdgcn_readfirstlane(csr_boff[i + 1]);
        int b2 = __builtin_amdgcn_readfirstlane(csr_boff[i + 2]);
        int b3 = __builtin_amdgcn_readfirstlane(csr_boff[i + 3]);
        u0 = *(const ushort4*)(xlc + b0 + lo8);
        u1 = *(const ushort4*)(xlc + b1 + lo8);
        u2 = *(const ushort4*)(xlc + b2 + lo8);
        u3 = *(const ushort4*)(xlc + b3 + lo8);
    }
    if (i + 4 < imend) {
        int b0 = __builtin_amdgcn_readfirstlane(csr_boff[i + 4]);
        int b1 = __builtin_amdgcn_readfirstlane(csr_boff[i + 5]);
        int b2 = __builtin_amdgcn_readfirstlane(csr_boff[i + 6]);
        int b3 = __builtin_amdgcn_readfirstlane(csr_boff[i + 7]);
        v0 = *(const ushort4*)(xlc + b0 + lo8);
        v1 = *(const ushort4*)(xlc + b1 + lo8);
        v2 = *(const ushort4*)(xlc + b2 + lo8);
        v3 = *(const ushort4*)(xlc + b3 + lo8);
    }
    while (i < imend) {
        ushort4 c0 = u0, c1 = u1, c2 = u2, c3 = u3;
        u0 = v0; u1 = v1; u2 = v2; u3 = v3;
        int ipf = i + 8;
        if (ipf < imend) {         // prefetch 2 groups ahead
            int b0 = __builtin_amdgcn_readfirstlane(csr_boff[ipf]);
            int b1 = __builtin_amdgcn_readfirstlane(csr_boff[ipf + 1]);
            int b2 = __builtin_amdgcn_readfirstlane(csr_boff[ipf + 2]);
            int b3 = __builtin_amdgcn_readfirstlane(csr_boff[ipf + 3]);
            v0 = *(const ushort4*)(xlc + b0 + lo8);
            v1 = *(const ushort4*)(xlc + b1 + lo8);
            v2 = *(const ushort4*)(xlc + b2 + lo8);
            v3 = *(const ushort4*)(xlc + b3 + lo8);
        }
        float f0[4], f1[4], f2[4], f3[4];
        unpk(c0, f0); unpk(c1, f1); unpk(c2, f2); unpk(c3, f3);

        float p0 = esc(f0, xr0, xr1, xr2, xr3, att4);
        float p1 = esc(f1, xr0, xr1, xr2, xr3, att4);
        float p2 = esc(f2, xr0, xr1, xr2, xr3, att4);
        float p3 = esc(f3, xr0, xr1, xr2, xr3, att4);

        p0 = dppadd<0xB1>(p0);  p1 = dppadd<0xB1>(p1);  p2 = dppadd<0xB1>(p2);  p3 = dppadd<0xB1>(p3);
        p0 = dppadd<0x4E>(p0);  p1 = dppadd<0x4E>(p1);  p2 = dppadd<0x4E>(p2);  p3 = dppadd<0x4E>(p3);
        p0 = dppadd<0x124>(p0); p1 = dppadd<0x124>(p1); p2 = dppadd<0x124>(p2); p3 = dppadd<0x124>(p3);
        p0 = dppadd<0x128>(p0); p1 = dppadd<0x128>(p1); p2 = dppadd<0x128>(p2); p3 = dppadd<0x128>(p3);

        float e0 = EXP2F(p0), e1 = EXP2F(p1);
        float e2 = EXP2F(p2), e3 = EXP2F(p3);
        ax = fmaf(e0, f0[0], fmaf(e1, f1[0], fmaf(e2, f2[0], fmaf(e3, f3[0], ax))));
        ay = fmaf(e0, f0[1], fmaf(e1, f1[1], fmaf(e2, f2[1], fmaf(e3, f3[1], ay))));
        az = fmaf(e0, f0[2], fmaf(e1, f1[2], fmaf(e2, f2[2], fmaf(e3, f3[2], az))));
        aw = fmaf(e0, f0[3], fmaf(e1, f1[3], fmaf(e2, f2[3], fmaf(e3, f3[3], aw))));
        lsum += (e0 + e1) + (e2 + e3);
        i += 4;
    }
    for (; i < end; ++i) {                 // tail (0..3 edges)
        int b0 = __builtin_amdgcn_readfirstlane(csr_boff[i]);
        ushort4 t0 = *(const ushort4*)(xlc + b0 + lo8);
        float f0[4];
        unpk(t0, f0);
        float p0 = esc(f0, xr0, xr1, xr2, xr3, att4);
        p0 = red16(p0);
        float e0 = EXP2F(p0);
        ax = fmaf(e0, f0[0], ax); ay = fmaf(e0, f0[1], ay);
        az = fmaf(e0, f0[2], az); aw = fmaf(e0, f0[3], aw);
        lsum += e0;
    }

    float inv = 1.f / (lsum + 1e-16f);
    float4 b4 = *(const float4*)(bias + 4 * lane);
    ushort4 o;
    o.x = f2bf(fmaf(ax, inv, b4.x));
    o.y = f2bf(fmaf(ay, inv, b4.y));
    o.z = f2bf(fmaf(az, inv, b4.z));
    o.w = f2bf(fmaf(aw, inv, b4.w));
    ((ushort4*)outb)[(size_t)d * 64 + lane] = o;
}

// ---------------- BatchNorm (bf16 input path) ----------------
__global__ __launch_bounds__(256) void bn_partial(const unsigned short* __restrict__ outb,
                                                  float* __restrict__ partials, int n)
{
    int c = threadIdx.x;
    int b = blockIdx.x;
    int chunk = (n + NB_BN - 1) / NB_BN;
    int beg = b * chunk;
    int end = min(beg + chunk, n);
    float s = 0.f, s2 = 0.f;
    for (int r = beg; r < end; ++r) {
        float v = bf2f(outb[(size_t)r * HC + c]);
        s += v; s2 += v * v;
    }
    partials[(size_t)b * 512 + c] = s;
    partials[(size_t)b * 512 + 256 + c] = s2;
}

// one block per channel
__global__ __launch_bounds__(256) void bn_final(const float* __restrict__ partials,
                                                float* __restrict__ stats, int n)
{
    int c = blockIdx.x;
    int t = threadIdx.x;
    float s = 0.f, s2 = 0.f;
    for (int b = t; b < NB_BN; b += 256) {
        s  += partials[(size_t)b * 512 + c];
        s2 += partials[(size_t)b * 512 + 256 + c];
    }
    __shared__ float rs[256], rs2[256];
    rs[t] = s; rs2[t] = s2;
    __syncthreads();
    for (int d = 128; d > 0; d >>= 1) {
        if (t < d) { rs[t] += rs[t + d]; rs2[t] += rs2[t + d]; }
        __syncthreads();
    }
    if (t == 0) {
        float mean = rs[0] / (float)n;
        float var = rs2[0] / (float)n - mean * mean;
        stats[c] = mean;
        stats[256 + c] = rsqrtf(var + BN_EPS);
    }
}

__global__ void bn_apply(const unsigned short* __restrict__ outb,
                         const float* __restrict__ stats,
                         const float* __restrict__ gamma, const float* __restrict__ beta,
                         float* __restrict__ out, long long total4)
{
    long long stride = (long long)gridDim.x * blockDim.x;
    for (long long i = blockIdx.x * (long long)blockDim.x + threadIdx.x; i < total4;
         i += stride) {
        int cb = ((int)(i & 63)) * 4;
        ushort4 u = ((const ushort4*)outb)[i];
        float4 o;
        o.x = fmaxf(0.f, (bf2f(u.x) - stats[cb + 0]) * stats[256 + cb + 0] * gamma[cb + 0] + beta[cb + 0]);
        o.y = fmaxf(0.f, (bf2f(u.y) - stats[cb + 1]) * stats[256 + cb + 1] * gamma[cb + 1] + beta[cb + 1]);
        o.z = fmaxf(0.f, (bf2f(u.z) - stats[cb + 2]) * stats[256 + cb + 2] * gamma[cb + 2] + beta[cb + 2]);
        o.w = fmaxf(0.f, (bf2f(u.w) - stats[cb + 3]) * stats[256 + cb + 3] * gamma[cb + 3] + beta[cb + 3]);
        ((float4*)out)[i] = o;
    }
}

// ---------------- launch ----------------
extern "C" void kernel_launch(void* const* d_in, const int* in_sizes, int n_in,
                              void* d_out, int out_size, void* d_ws, size_t ws_size,
                              hipStream_t stream)
{
    const float* feature = (const float*)d_in[0];
    const int* ei        = (const int*)d_in[1];
    const float* Wl   = (const float*)d_in[2];
    const float* bl   = (const float*)d_in[3];
    const float* Wr   = (const float*)d_in[4];
    const float* br   = (const float*)d_in[5];
    const float* att  = (const float*)d_in[6];
    const float* bias = (const float*)d_in[7];
    const float* gamma = (const float*)d_in[8];
    const float* beta  = (const float*)d_in[9];

    const int n = in_sizes[0] / IN_DIM;
    const int E = in_sizes[1] / 2;
    const int ntiles = (n + 15) / 16;
    const int nbkt = (n + 511) >> 9;

    char* ws = (char*)d_ws;
    size_t o = 0;
    auto carve = [&](size_t bytes) -> void* {
        void* p = ws + o; o = (o + bytes + 15) & ~(size_t)15; return p;
    };
    unsigned short* xl    = (unsigned short*)carve((size_t)n * HC * sizeof(short));
    unsigned short* xr    = (unsigned short*)carve((size_t)n * HC * sizeof(short));
    unsigned short* outb  = (unsigned short*)carve((size_t)n * HC * sizeof(short));
    unsigned short* Wfrag = (unsigned short*)carve((size_t)32 * 4 * 64 * 8 * sizeof(short));
    int2* bucketBuf = (int2*)carve((size_t)256 * BKT_CAP * sizeof(int2));
    int*  csr_boff  = (int*)carve((size_t)E * sizeof(int));
    int*  off       = (int*)carve((size_t)(n + 1) * sizeof(int));
    int*  gcur      = (int*)carve(256 * sizeof(int));
    float* partials = (float*)carve((size_t)NB_BN * 512 * sizeof(float));
    float* stats    = (float*)carve(512 * sizeof(float));
    float* outf = (float*)d_out;

    if (o > ws_size) return;

    // 1. prep: cast W fragments + zero bucket cursors
    prep<<<33, 256, 0, stream>>>(Wl, Wr, Wfrag, gcur);

    // 2. K1: LDS-sorted bucket scatter || gemm
    scatter_gemm<<<B_SC + (ntiles + 3) / 4, 256, 0, stream>>>(
        feature, Wfrag, bl, br, xl, xr, ei, gcur, bucketBuf, E, n, ntiles);

    // 3. K2: per-bucket CSR build
    bucket_build<<<nbkt, 256, 0, stream>>>(bucketBuf, gcur, off, csr_boff, n, nbkt);

    // 4. per-node aggregation
    int agg_blocks = (n + 3) / 4;
    gat_agg<<<agg_blocks, 256, 0, stream>>>(xl, xr, csr_boff, off, att, bias, outb, n);

    // 5. BN partial + finalize + apply
    bn_partial<<<NB_BN, 256, 0, stream>>>(outb, partials, n);
    bn_final<<<256, 256, 0, stream>>>(partials, stats, n);
    long long total4 = (long long)n * (HC / 4);
    bn_apply<<<4096, 256, 0, stream>>>(outb, stats, gamma, beta, outf, total4);
}